// Round 3
// baseline (3553.102 us; speedup 1.0000x reference)
//
#include <hip/hip_runtime.h>
#include <hip/hip_bf16.h>
#include <math.h>

#define VB 50000
#define EE 256
#define UU 512
#define BB 256
#define TT 256
#define G4 2048

typedef __attribute__((ext_vector_type(8))) short short8;
typedef __attribute__((ext_vector_type(4))) float f32x4;

__device__ __forceinline__ float sigf(float x){ return 1.0f/(1.0f+expf(-x)); }
__device__ __forceinline__ unsigned short f2bf(float f){
    __hip_bfloat16 h = __float2bfloat16(f);   // RNE
    unsigned short s; __builtin_memcpy(&s,&h,2); return s;
}
__device__ __forceinline__ float bf2f(unsigned short u){
    unsigned int x = ((unsigned int)u)<<16; float f; __builtin_memcpy(&f,&x,4); return f;
}

// 16-byte device-coherent load as 2x8B agent-scope relaxed atomics (bypass
// stale per-CU L1 / per-XCD L2; served at the coherent point).
struct AF { unsigned long long a, b; };
__device__ __forceinline__ AF cload16(const unsigned short* p){
    const unsigned long long* q = (const unsigned long long*)p;
    AF r;
    r.a = __hip_atomic_load(q,   __ATOMIC_RELAXED, __HIP_MEMORY_SCOPE_AGENT);
    r.b = __hip_atomic_load(q+1, __ATOMIC_RELAXED, __HIP_MEMORY_SCOPE_AGENT);
    return r;
}
__device__ __forceinline__ short8 af2v(AF x){
    union { unsigned long long u[2]; short8 v; } c; c.u[0]=x.a; c.u[1]=x.b; return c.v;
}
__device__ __forceinline__ unsigned int cldu(const unsigned int* p){
    return __hip_atomic_load(p, __ATOMIC_RELAXED, __HIP_MEMORY_SCOPE_AGENT);
}
__device__ __forceinline__ void cstu(unsigned int* p, unsigned int v){
    __hip_atomic_store(p, v, __ATOMIC_RELAXED, __HIP_MEMORY_SCOPE_AGENT);
}

// ---------- pre-pass: transpose+convert W [rows][2048] fp32 -> out[c][koff+k] bf16 ----------
__global__ __launch_bounds__(256) void wtrans(const float* __restrict__ in, int rows,
                                              unsigned short* __restrict__ out,
                                              int Kout, int koff) {
    __shared__ float tl[32][33];
    int tx = threadIdx.x, ty = threadIdx.y;
    int c0 = blockIdx.x * 32, k0 = blockIdx.y * 32;
    #pragma unroll
    for (int i = 0; i < 4; i++)
        tl[ty + i * 8][tx] = in[(size_t)(k0 + ty + i * 8) * G4 + c0 + tx];
    __syncthreads();
    #pragma unroll
    for (int i = 0; i < 4; i++)
        out[(size_t)(c0 + ty + i * 8) * Kout + koff + k0 + tx] = f2bf(tl[tx][ty + i * 8]);
}

// ---------- pre-pass: gather embeddings -> xbf[t][b][k] bf16 ----------
__global__ __launch_bounds__(64) void xgather(const int* __restrict__ tokens,
                                              const float* __restrict__ emb,
                                              unsigned short* __restrict__ xbf) {
    int flat = blockIdx.x;
    int b = flat & 255, t = flat >> 8;
    int tok = tokens[b * TT + t];
    float4 v = ((const float4*)(emb + (size_t)tok * EE))[threadIdx.x];
    ushort4 o;
    o.x = f2bf(v.x); o.y = f2bf(v.y); o.z = f2bf(v.z); o.w = f2bf(v.w);
    ((ushort4*)(xbf + ((size_t)t * BB + b) * EE))[threadIdx.x] = o;
}

// ---------- persistent 2-layer LSTM ----------
// 4 groups x 64 blocks; group g owns batch rows [g*64, g*64+64).
// local 0..31 = layer0 (K=768: x|h0), 32..63 = layer1 (K=1024: h0|h1); 16 u's/block.
// Sync protocol = round-0 verbatim (harness-verified): 64 per-block flags per
// group, PER-WAVE lane-parallel polling (lane L polls flag of block L), flag
// store by tid0 after vmcnt-drain + barrier.
// Changes vs round 0 (post-arrival compute segment only):
//  * LDS weight chunks LANE-ordered: lane l reads bytes [l*16,l*16+16) of each
//    1KB (gate,kt) tile -> ds_read_b128 fully linear, zero bank conflicts
//    (was 4-way conflict on every weight read: SQ_LDS_BANK_CONFLICT 1.17e8).
//  * MFMA operands swapped (A=weight frag, B=x/h frag; fragment layouts are
//    symmetric so same loads serve both roles; same k-order sums -> bit-safe).
//    D is transposed: col=n16->batch, row=q*4+r->unit. Each thread owns 4
//    consecutive units of one batch row -> h store is ONE packed 8B agent
//    store; no LDS staging, no second barrier.
//  * Full-depth A pipelines: all 16 (L0) / 32 (L1) h-chunks issued at once ->
//    one exposed LLC latency per step.
__global__ __launch_bounds__(256, 1) void rnn_persist(
    const unsigned short* __restrict__ Wt0,   // [2048][768]  bf16 [col][k]
    const unsigned short* __restrict__ Wt1,   // [2048][1024]
    const unsigned short* __restrict__ xbf,   // [256][256][256] bf16 (or unused)
    const int* __restrict__ tokens, const float* __restrict__ emb,
    const float* __restrict__ b0v, const float* __restrict__ b1v,
    unsigned short* __restrict__ h0buf,       // [4][256][512] bf16 ring
    unsigned short* __restrict__ h1buf,       // [2][256][512] bf16 ring
    unsigned int* __restrict__ bars,          // per group 1024 uints (4KB)
    int use_xbf)
{
    extern __shared__ char smem[];
    unsigned short* wl  = (unsigned short*)smem;        // lane-ordered weights (<=128KB)
    int*            tokl = (int*)(smem + 131072);       // 64 ints

    const int tid   = threadIdx.x;
    const int bid   = blockIdx.x;
    const int g     = bid >> 6;
    const int local = bid & 63;
    const int layer = local >> 5;
    const int u0    = (local & 31) * 16;
    const int row0  = g * 64;
    const int K     = layer ? 1024 : 768;
    const int KT    = K / 32;                  // 24 or 32 k-tiles
    const unsigned short* Wt = layer ? Wt1 : Wt0;
    const float* bR = layer ? b1v : b0v;

    // ---- fill LDS weights, LANE-ordered chunks: i = ((gate*KT+kt)*64 + (q*16+n)) ----
    const int nch = 4 * KT * 64;
    for (int i = tid; i < nch; i += 256) {
        int n  = i & 15;
        int q2 = (i >> 4) & 3;
        int t2 = i >> 6;
        int kt = t2 % KT, gate = t2 / KT;
        const unsigned short* src = Wt + (size_t)(gate * UU + u0 + n) * K + kt * 32 + q2 * 8;
        *(short8*)(wl + (size_t)i * 8) = *(const short8*)src;
    }

    const int lane = tid & 63;
    const int w    = tid >> 6;
    const int n16  = lane & 15;
    const int q    = lane >> 4;
    const int q8   = q * 8;
    const int myrow = row0 + w * 16 + n16;
    const unsigned short* wlane = wl + lane * 8;   // + (gate*KT+kt)*512 shorts

    // bias per (gate, unit = u0 + q*4 + r)  -- D-transposed layout
    float gb4[4][4];
    #pragma unroll
    for (int gate = 0; gate < 4; gate++)
        #pragma unroll
        for (int r = 0; r < 4; r++)
            gb4[gate][r] = bR[gate * UU + u0 + q * 4 + r];
    float cst[4] = {0.f, 0.f, 0.f, 0.f};

    // flag region for this group: flag(local) at 16B stride
    unsigned int* flg = bars + (size_t)g * 1024;
    unsigned int* myFlag = flg + local * 4;
    // per-lane poll target: lane L polls flag of block L
    const unsigned int* pollp = flg + lane * 4;
    const int pollSlack = (layer == 0 && lane >= 32) ? 2 : 0;  // L0 waits L1>=p-2

    const size_t HS = (size_t)BB * UU;

    __syncthreads();   // wl ready

    for (int p = 0; p <= TT; p++) {
        const bool active = layer ? (p >= 1) : (p < TT);
        const bool wait_needed = layer ? (p >= 1) : (p < TT);

        f32x4 acc[4];
        #pragma unroll
        for (int gate = 0; gate < 4; gate++)
            acc[gate] = (f32x4){gb4[gate][0], gb4[gate][1], gb4[gate][2], gb4[gate][3]};

        // ---- L0 x-part precompute (static inputs only) BEFORE the wait ----
        short8 xv[8];
        if (layer == 0 && p < TT) {
            if (!use_xbf) {
                if (tid < 64) tokl[tid] = tokens[(size_t)(row0 + tid) * TT + p];
                __syncthreads();
                const float* ep = emb + (size_t)tokl[w * 16 + n16] * EE + q8;
                #pragma unroll
                for (int kt = 0; kt < 8; kt++) {
                    float4 f0 = *(const float4*)(ep + kt * 32);
                    float4 f1 = *(const float4*)(ep + kt * 32 + 4);
                    union { unsigned short s[8]; short8 v; } u;
                    u.s[0]=f2bf(f0.x); u.s[1]=f2bf(f0.y); u.s[2]=f2bf(f0.z); u.s[3]=f2bf(f0.w);
                    u.s[4]=f2bf(f1.x); u.s[5]=f2bf(f1.y); u.s[6]=f2bf(f1.z); u.s[7]=f2bf(f1.w);
                    #pragma unroll
                    for (int gate = 0; gate < 4; gate++) {
                        short8 bv = *(const short8*)(wlane + (size_t)(gate * KT + kt) * 512);
                        acc[gate] = __builtin_amdgcn_mfma_f32_16x16x32_bf16(bv, u.v, acc[gate], 0, 0, 0);
                    }
                }
            } else {
                const unsigned short* xp = xbf + ((size_t)p * BB + myrow) * EE + q8;
                #pragma unroll
                for (int kt = 0; kt < 8; kt++)
                    xv[kt] = *(const short8*)(xp + kt * 32);
            }
        }

        // ---- per-wave direct poll: lane L polls flag of block L, no sync after ----
        if (wait_needed) {
            const int thr = p - pollSlack;
            for (;;) {
                bool bad = ((int)cldu(pollp) < thr);
                if (__ballot(bad) == 0ULL) break;
                __builtin_amdgcn_s_sleep(1);
            }
        }

        // ---- dynamic (h-dependent) part: full-depth A pipeline ----
        if (active) {
            const unsigned short* h0r = h0buf + (size_t)(p & 3) * HS;
            unsigned short* hw;

            if (layer) {
                const unsigned short* h1r = h1buf + (size_t)((p + 1) & 1) * HS;  // h1(p-1)
                hw = h1buf + (size_t)(p & 1) * HS;
                const unsigned short* a0 = h0r + (size_t)myrow * UU + q8;
                const unsigned short* a1 = h1r + (size_t)myrow * UU + q8;
                AF ha[16], hc[16];
                #pragma unroll
                for (int i = 0; i < 16; i++) ha[i] = cload16(a0 + i * 32);
                #pragma unroll
                for (int i = 0; i < 16; i++) hc[i] = cload16(a1 + i * 32);
                #pragma unroll
                for (int i = 0; i < 16; i++) {
                    short8 av = af2v(ha[i]);
                    #pragma unroll
                    for (int gate = 0; gate < 4; gate++) {
                        short8 bv = *(const short8*)(wlane + (size_t)(gate * KT + i) * 512);
                        acc[gate] = __builtin_amdgcn_mfma_f32_16x16x32_bf16(bv, av, acc[gate], 0, 0, 0);
                    }
                }
                #pragma unroll
                for (int i = 0; i < 16; i++) {
                    short8 av = af2v(hc[i]);
                    #pragma unroll
                    for (int gate = 0; gate < 4; gate++) {
                        short8 bv = *(const short8*)(wlane + (size_t)(gate * KT + 16 + i) * 512);
                        acc[gate] = __builtin_amdgcn_mfma_f32_16x16x32_bf16(bv, av, acc[gate], 0, 0, 0);
                    }
                }
            } else {
                hw = h0buf + (size_t)((p + 1) & 3) * HS;
                const unsigned short* ah = h0r + (size_t)myrow * UU + q8;
                AF hb[16];
                #pragma unroll
                for (int i = 0; i < 16; i++) hb[i] = cload16(ah + i * 32);
                if (use_xbf) {
                    #pragma unroll
                    for (int kt = 0; kt < 8; kt++) {
                        #pragma unroll
                        for (int gate = 0; gate < 4; gate++) {
                            short8 bv = *(const short8*)(wlane + (size_t)(gate * KT + kt) * 512);
                            acc[gate] = __builtin_amdgcn_mfma_f32_16x16x32_bf16(bv, xv[kt], acc[gate], 0, 0, 0);
                        }
                    }
                }
                #pragma unroll
                for (int i = 0; i < 16; i++) {
                    short8 av = af2v(hb[i]);
                    #pragma unroll
                    for (int gate = 0; gate < 4; gate++) {
                        short8 bv = *(const short8*)(wlane + (size_t)(gate * KT + 8 + i) * 512);
                        acc[gate] = __builtin_amdgcn_mfma_f32_16x16x32_bf16(bv, av, acc[gate], 0, 0, 0);
                    }
                }
            }

            // gating (D^T: col=n16->batch, row=q*4+r->unit); ONE packed 8B store
            unsigned long long pk = 0;
            #pragma unroll
            for (int r = 0; r < 4; r++) {
                float zi = acc[0][r];
                float zf = acc[1][r];
                float zg = acc[2][r];
                float zo = acc[3][r];
                float cn = sigf(zf) * cst[r] + sigf(zi) * tanhf(zg);
                cst[r] = cn;
                pk |= (unsigned long long)f2bf(sigf(zo) * tanhf(cn)) << (16 * r);
            }
            __hip_atomic_store((unsigned long long*)(hw + (size_t)myrow * UU + u0 + q * 4),
                               pk, __ATOMIC_RELAXED, __HIP_MEMORY_SCOPE_AGENT);
        }

        // ---- arrive(p): every wave drains its own vmem, then tid0 flags ----
        if (p < TT) {
            asm volatile("s_waitcnt vmcnt(0)" ::: "memory");
            __syncthreads();
            if (tid == 0) cstu(myFlag, (unsigned int)(p + 1));
        }
    }
}

// ---------- final dense: out[b] = sigmoid(h1 . Wd + bd) ----------
__global__ __launch_bounds__(64) void dense_out(
    const unsigned short* __restrict__ h, const float* __restrict__ Wd,
    const float* __restrict__ bd, float* __restrict__ out)
{
    int b = blockIdx.x;
    int lane = threadIdx.x;
    float s = 0.f;
    #pragma unroll
    for (int k = lane; k < UU; k += 64) s += bf2f(h[(size_t)b * UU + k]) * Wd[k];
    #pragma unroll
    for (int off = 32; off > 0; off >>= 1) s += __shfl_down(s, off);
    if (lane == 0) out[b] = sigf(s + bd[0]);
}

extern "C" void kernel_launch(void* const* d_in, const int* in_sizes, int n_in,
                              void* d_out, int out_size, void* d_ws, size_t ws_size,
                              hipStream_t stream) {
    const int*   tokens = (const int*)  d_in[0];
    const float* emb    = (const float*)d_in[1];
    const float* W0     = (const float*)d_in[2];
    const float* U0     = (const float*)d_in[3];
    const float* b0     = (const float*)d_in[4];
    const float* W1     = (const float*)d_in[5];
    const float* U1     = (const float*)d_in[6];
    const float* b1     = (const float*)d_in[7];
    const float* Wd     = (const float*)d_in[8];
    const float* bd     = (const float*)d_in[9];
    float* out = (float*)d_out;

    // ws layout (bytes):
    // [Wt0 3MB][Wt1 4MB][h0 ring x4 1MB][h1 ring x2 0.5MB][bars 32KB][xbf 32MB]
    const size_t oWt0 = 0;
    const size_t oWt1 = (size_t)G4 * 768 * 2;                 // 3,145,728
    const size_t oH0  = oWt1 + (size_t)G4 * 1024 * 2;         // 7,340,032
    const size_t oH1  = oH0 + (size_t)4 * BB * UU * 2;        // +1,048,576
    const size_t oBar = oH1 + (size_t)2 * BB * UU * 2;        // +524,288
    const size_t oX   = oBar + 32768;
    const size_t needFull = oX + (size_t)TT * BB * EE * 2;    // ~42.5 MB
    int use_xbf = (ws_size >= needFull) ? 1 : 0;

    unsigned short* Wt0p = (unsigned short*)((char*)d_ws + oWt0);
    unsigned short* Wt1p = (unsigned short*)((char*)d_ws + oWt1);
    unsigned short* h0p  = (unsigned short*)((char*)d_ws + oH0);
    unsigned short* h1p  = (unsigned short*)((char*)d_ws + oH1);
    unsigned int*   barp = (unsigned int*)  ((char*)d_ws + oBar);
    unsigned short* xbfp = (unsigned short*)((char*)d_ws + oX);

    hipMemsetAsync((char*)d_ws + oH0, 0, oX - oH0, stream);

    wtrans<<<dim3(G4 / 32, EE / 32), dim3(32, 8), 0, stream>>>(W0, EE, Wt0p, 768, 0);
    wtrans<<<dim3(G4 / 32, UU / 32), dim3(32, 8), 0, stream>>>(U0, UU, Wt0p, 768, 256);
    wtrans<<<dim3(G4 / 32, UU / 32), dim3(32, 8), 0, stream>>>(W1, UU, Wt1p, 1024, 0);
    wtrans<<<dim3(G4 / 32, UU / 32), dim3(32, 8), 0, stream>>>(U1, UU, Wt1p, 1024, 512);

    if (use_xbf)
        xgather<<<dim3(BB * TT), dim3(64), 0, stream>>>(tokens, emb, xbfp);

    {
        const size_t shmem = 131072 + 256;   // wl + tokl
        hipFuncSetAttribute((const void*)rnn_persist,
                            hipFuncAttributeMaxDynamicSharedMemorySize, (int)shmem);
        void* args[] = {(void*)&Wt0p, (void*)&Wt1p, (void*)&xbfp,
                        (void*)&tokens, (void*)&emb, (void*)&b0, (void*)&b1,
                        (void*)&h0p, (void*)&h1p, (void*)&barp, (void*)&use_xbf};
        hipLaunchCooperativeKernel((const void*)rnn_persist, dim3(256), dim3(256),
                                   args, shmem, stream);
    }

    dense_out<<<dim3(BB), dim3(64), 0, stream>>>(h1p, Wd, bd, out);   // h1(256) = slot 0
}

// Round 4
// 3156.170 us; speedup vs baseline: 1.1258x; 1.1258x over previous
//
#include <hip/hip_runtime.h>
#include <hip/hip_bf16.h>
#include <math.h>

#define VB 50000
#define EE 256
#define UU 512
#define BB 256
#define TT 256
#define G4 2048

typedef __attribute__((ext_vector_type(8))) short short8;
typedef __attribute__((ext_vector_type(4))) float f32x4;

__device__ __forceinline__ float sigf(float x){ return 1.0f/(1.0f+expf(-x)); }
__device__ __forceinline__ unsigned short f2bf(float f){
    __hip_bfloat16 h = __float2bfloat16(f);   // RNE
    unsigned short s; __builtin_memcpy(&s,&h,2); return s;
}
__device__ __forceinline__ float bf2f(unsigned short u){
    unsigned int x = ((unsigned int)u)<<16; float f; __builtin_memcpy(&f,&x,4); return f;
}

// 16-byte device-coherent load as 2x8B agent-scope relaxed atomics (bypass
// stale per-CU L1 / per-XCD L2; served at the coherent point).
struct AF { unsigned long long a, b; };
__device__ __forceinline__ AF cload16(const unsigned short* p){
    const unsigned long long* q = (const unsigned long long*)p;
    AF r;
    r.a = __hip_atomic_load(q,   __ATOMIC_RELAXED, __HIP_MEMORY_SCOPE_AGENT);
    r.b = __hip_atomic_load(q+1, __ATOMIC_RELAXED, __HIP_MEMORY_SCOPE_AGENT);
    return r;
}
__device__ __forceinline__ short8 af2v(AF x){
    union { unsigned long long u[2]; short8 v; } c; c.u[0]=x.a; c.u[1]=x.b; return c.v;
}
__device__ __forceinline__ unsigned int cldu(const unsigned int* p){
    return __hip_atomic_load(p, __ATOMIC_RELAXED, __HIP_MEMORY_SCOPE_AGENT);
}
__device__ __forceinline__ void cstu(unsigned int* p, unsigned int v){
    __hip_atomic_store(p, v, __ATOMIC_RELAXED, __HIP_MEMORY_SCOPE_AGENT);
}

// ---------- pre-pass: transpose+convert W [rows][2048] fp32 -> out[c][koff+k] bf16 ----------
__global__ __launch_bounds__(256) void wtrans(const float* __restrict__ in, int rows,
                                              unsigned short* __restrict__ out,
                                              int Kout, int koff) {
    __shared__ float tl[32][33];
    int tx = threadIdx.x, ty = threadIdx.y;
    int c0 = blockIdx.x * 32, k0 = blockIdx.y * 32;
    #pragma unroll
    for (int i = 0; i < 4; i++)
        tl[ty + i * 8][tx] = in[(size_t)(k0 + ty + i * 8) * G4 + c0 + tx];
    __syncthreads();
    #pragma unroll
    for (int i = 0; i < 4; i++)
        out[(size_t)(c0 + ty + i * 8) * Kout + koff + k0 + tx] = f2bf(tl[tx][ty + i * 8]);
}

// ---------- pre-pass: gather embeddings -> xbf[t][b][k] bf16 ----------
__global__ __launch_bounds__(64) void xgather(const int* __restrict__ tokens,
                                              const float* __restrict__ emb,
                                              unsigned short* __restrict__ xbf) {
    int flat = blockIdx.x;
    int b = flat & 255, t = flat >> 8;
    int tok = tokens[b * TT + t];
    float4 v = ((const float4*)(emb + (size_t)tok * EE))[threadIdx.x];
    ushort4 o;
    o.x = f2bf(v.x); o.y = f2bf(v.y); o.z = f2bf(v.z); o.w = f2bf(v.w);
    ((ushort4*)(xbf + ((size_t)t * BB + b) * EE))[threadIdx.x] = o;
}

// ---------- persistent 2-layer LSTM ----------
// STRUCTURE = round-0 verbatim (best verified: 3015us, absmax 0.0):
//   4 groups x 64 blocks; local 0..31 = layer0 (K=768), 32..63 = layer1 (K=1024).
//   hst LDS staging + 128-thread coalesced 16B h-stores; 2-stage register A
//   pipeline; L0 x-part (loads AND MFMAs) before the wait; per-wave polling.
// Changes vs round 0 -- sync-path only, arithmetic bit-identical:
//  1) LDS weight chunks LANE-ordered (chunk (q*16+n) -> lane l reads bytes
//     [l*16,l*16+16) of each 1KB tile): ds_read_b128 conflict-free (R3-proven:
//     SQ_LDS_BANK_CONFLICT 1.18e8 -> 0). Same chunk contents, placement only.
//  2) Flags packed at 4B stride (was 16B): a wave's 64-lane poll coalesces
//     into 4 cache-line fetches instead of 16 -> 4x poll traffic cut on the
//     hot flag lines at the coherent point.
//  3) Hot-spin poll (no s_sleep): faster detect; keeps SQ busy so the clock
//     governor sees activity (suspected DPM down-clock at 90%-sleep duty).
__global__ __launch_bounds__(256, 1) void rnn_persist(
    const unsigned short* __restrict__ Wt0,   // [2048][768]  bf16 [col][k]
    const unsigned short* __restrict__ Wt1,   // [2048][1024]
    const unsigned short* __restrict__ xbf,   // [256][256][256] bf16 (or unused)
    const int* __restrict__ tokens, const float* __restrict__ emb,
    const float* __restrict__ b0v, const float* __restrict__ b1v,
    unsigned short* __restrict__ h0buf,       // [4][256][512] bf16 ring
    unsigned short* __restrict__ h1buf,       // [2][256][512] bf16 ring
    unsigned int* __restrict__ bars,          // per group 1024 uints (4KB)
    int use_xbf)
{
    extern __shared__ char smem[];
    unsigned short* wl  = (unsigned short*)smem;               // lane-ordered weights (<=128KB)
    unsigned short* hst = (unsigned short*)(smem + 131072);    // 64x16 h staging, stride 24 (3KB)
    int*            tokl = (int*)(smem + 131072 + 3072);       // 64 ints

    const int tid   = threadIdx.x;
    const int bid   = blockIdx.x;
    const int g     = bid >> 6;
    const int local = bid & 63;
    const int layer = local >> 5;
    const int u0    = (local & 31) * 16;
    const int row0  = g * 64;
    const int K     = layer ? 1024 : 768;
    const int KT    = K / 32;                  // 24 or 32 k-tiles
    const unsigned short* Wt = layer ? Wt1 : Wt0;
    const float* bR = layer ? b1v : b0v;

    // ---- fill LDS weights, LANE-ordered chunks: i = ((gate*KT+kt)*64 + (q*16+n)) ----
    const int nch = 4 * KT * 64;
    for (int i = tid; i < nch; i += 256) {
        int n  = i & 15;
        int q2 = (i >> 4) & 3;
        int t2 = i >> 6;
        int kt = t2 % KT, gate = t2 / KT;
        const unsigned short* src = Wt + (size_t)(gate * UU + u0 + n) * K + kt * 32 + q2 * 8;
        *(short8*)(wl + (size_t)i * 8) = *(const short8*)src;
    }

    float gb[4];
    #pragma unroll
    for (int gate = 0; gate < 4; gate++) gb[gate] = bR[gate * UU + u0 + (tid & 15)];
    float cst[4] = {0.f, 0.f, 0.f, 0.f};

    const int lane = tid & 63;
    const int w    = tid >> 6;
    const int n16  = lane & 15;
    const int q    = lane >> 4;
    const int q8   = q * 8;
    const int myrow = row0 + w * 16 + n16;
    const unsigned short* wlane = wl + lane * 8;   // + (gate*KT+kt)*512 shorts

    // flag region for this group: flag(local) at 4B stride (coalesced polls)
    unsigned int* flg = bars + (size_t)g * 1024;
    unsigned int* myFlag = flg + local;
    // per-lane poll target: lane L polls flag of block L
    const unsigned int* pollp = flg + lane;
    const int pollSlack = (layer == 0 && lane >= 32) ? 2 : 0;  // L0 waits L1>=p-2

    const size_t HS = (size_t)BB * UU;

    __syncthreads();   // wl ready

    for (int p = 0; p <= TT; p++) {
        const bool active = layer ? (p >= 1) : (p < TT);
        const bool wait_needed = layer ? (p >= 1) : (p < TT);

        f32x4 acc[4];
        #pragma unroll
        for (int gate = 0; gate < 4; gate++)
            acc[gate] = (f32x4){gb[gate], gb[gate], gb[gate], gb[gate]};

        // ---- L0 x-part precompute (static inputs only) BEFORE the wait ----
        if (layer == 0 && p < TT) {
            if (!use_xbf) {
                if (tid < 64) tokl[tid] = tokens[(size_t)(row0 + tid) * TT + p];
                __syncthreads();
                const float* ep = emb + (size_t)tokl[w * 16 + n16] * EE + q8;
                #pragma unroll
                for (int kt = 0; kt < 8; kt++) {
                    float4 f0 = *(const float4*)(ep + kt * 32);
                    float4 f1 = *(const float4*)(ep + kt * 32 + 4);
                    union { unsigned short s[8]; short8 v; } u;
                    u.s[0]=f2bf(f0.x); u.s[1]=f2bf(f0.y); u.s[2]=f2bf(f0.z); u.s[3]=f2bf(f0.w);
                    u.s[4]=f2bf(f1.x); u.s[5]=f2bf(f1.y); u.s[6]=f2bf(f1.z); u.s[7]=f2bf(f1.w);
                    #pragma unroll
                    for (int gate = 0; gate < 4; gate++) {
                        short8 bv = *(const short8*)(wlane + (size_t)(gate * KT + kt) * 512);
                        acc[gate] = __builtin_amdgcn_mfma_f32_16x16x32_bf16(u.v, bv, acc[gate], 0, 0, 0);
                    }
                }
            } else {
                const unsigned short* xp = xbf + ((size_t)p * BB + myrow) * EE + q8;
                #pragma unroll
                for (int kt = 0; kt < 8; kt++) {
                    short8 av = *(const short8*)(xp + kt * 32);
                    #pragma unroll
                    for (int gate = 0; gate < 4; gate++) {
                        short8 bv = *(const short8*)(wlane + (size_t)(gate * KT + kt) * 512);
                        acc[gate] = __builtin_amdgcn_mfma_f32_16x16x32_bf16(av, bv, acc[gate], 0, 0, 0);
                    }
                }
            }
        }

        // ---- per-wave direct poll: lane L polls flag of block L; HOT spin ----
        if (wait_needed) {
            const int thr = p - pollSlack;
            for (;;) {
                bool bad = ((int)cldu(pollp) < thr);
                if (__ballot(bad) == 0ULL) break;
            }
        }

        // ---- dynamic (h-dependent) part: register-bounded A pipeline ----
        if (active) {
            const unsigned short* h0r = h0buf + (size_t)(p & 3) * HS;
            unsigned short* hw;

            if (layer) {
                const unsigned short* h1r = h1buf + (size_t)((p + 1) & 1) * HS;  // h1(p-1)
                hw = h1buf + (size_t)(p & 1) * HS;
                const unsigned short* a0 = h0r + (size_t)myrow * UU + q8;
                const unsigned short* a1 = h1r + (size_t)myrow * UU + q8;
                AF ab[2][8];
                #pragma unroll
                for (int i = 0; i < 8; i++) ab[0][i] = cload16(a0 + i * 32);  // stage 0
                #pragma unroll
                for (int s = 0; s < 4; s++) {
                    const int cur = s & 1, nxt = cur ^ 1;
                    if (s < 3) {
                        #pragma unroll
                        for (int i = 0; i < 8; i++) {
                            int kt = (s + 1) * 8 + i;
                            const unsigned short* ap = (kt < 16) ? (a0 + kt * 32)
                                                                 : (a1 + (kt - 16) * 32);
                            ab[nxt][i] = cload16(ap);
                        }
                    }
                    #pragma unroll
                    for (int i = 0; i < 8; i++) {
                        int kt = s * 8 + i;
                        short8 av = af2v(ab[cur][i]);
                        #pragma unroll
                        for (int gate = 0; gate < 4; gate++) {
                            short8 bv = *(const short8*)(wlane + (size_t)(gate * KT + kt) * 512);
                            acc[gate] = __builtin_amdgcn_mfma_f32_16x16x32_bf16(av, bv, acc[gate], 0, 0, 0);
                        }
                    }
                }
            } else {
                hw = h0buf + (size_t)((p + 1) & 3) * HS;
                const unsigned short* ah = h0r + (size_t)myrow * UU + q8;
                AF ab[2][8];
                #pragma unroll
                for (int i = 0; i < 8; i++) ab[0][i] = cload16(ah + i * 32);  // kt 8..15
                #pragma unroll
                for (int s = 0; s < 2; s++) {
                    const int cur = s & 1, nxt = cur ^ 1;
                    if (s < 1) {
                        #pragma unroll
                        for (int i = 0; i < 8; i++)
                            ab[nxt][i] = cload16(ah + (8 + i) * 32);          // kt 16..23
                    }
                    #pragma unroll
                    for (int i = 0; i < 8; i++) {
                        int kt = 8 + s * 8 + i;
                        short8 av = af2v(ab[cur][i]);
                        #pragma unroll
                        for (int gate = 0; gate < 4; gate++) {
                            short8 bv = *(const short8*)(wlane + (size_t)(gate * KT + kt) * 512);
                            acc[gate] = __builtin_amdgcn_mfma_f32_16x16x32_bf16(av, bv, acc[gate], 0, 0, 0);
                        }
                    }
                }
            }

            // gating (D layout: col=n16 -> u, row=q*4+r); stage h to LDS (stride 24)
            #pragma unroll
            for (int r = 0; r < 4; r++) {
                float zi = acc[0][r];
                float zf = acc[1][r];
                float zg = acc[2][r];
                float zo = acc[3][r];
                float cn = sigf(zf) * cst[r] + sigf(zi) * tanhf(zg);
                cst[r] = cn;
                hst[(w * 16 + q * 4 + r) * 24 + n16] = f2bf(sigf(zo) * tanhf(cn));
            }
            __syncthreads();   // hst complete (block-uniform path)
            if (tid < 128) {   // coalesced coherent store: 128 threads x 16B
                int row = tid >> 1, half = tid & 1;
                const unsigned long long* s = (const unsigned long long*)(hst + row * 24 + half * 8);
                unsigned long long* dp = (unsigned long long*)(hw + (size_t)(row0 + row) * UU + u0 + half * 8);
                __hip_atomic_store(dp,     s[0], __ATOMIC_RELAXED, __HIP_MEMORY_SCOPE_AGENT);
                __hip_atomic_store(dp + 1, s[1], __ATOMIC_RELAXED, __HIP_MEMORY_SCOPE_AGENT);
            }
        }

        // ---- arrive(p): every wave drains its own vmem, then tid0 flags ----
        if (p < TT) {
            asm volatile("s_waitcnt vmcnt(0)" ::: "memory");
            __syncthreads();
            if (tid == 0) cstu(myFlag, (unsigned int)(p + 1));
        }
    }
}

// ---------- final dense: out[b] = sigmoid(h1 . Wd + bd) ----------
__global__ __launch_bounds__(64) void dense_out(
    const unsigned short* __restrict__ h, const float* __restrict__ Wd,
    const float* __restrict__ bd, float* __restrict__ out)
{
    int b = blockIdx.x;
    int lane = threadIdx.x;
    float s = 0.f;
    #pragma unroll
    for (int k = lane; k < UU; k += 64) s += bf2f(h[(size_t)b * UU + k]) * Wd[k];
    #pragma unroll
    for (int off = 32; off > 0; off >>= 1) s += __shfl_down(s, off);
    if (lane == 0) out[b] = sigf(s + bd[0]);
}

extern "C" void kernel_launch(void* const* d_in, const int* in_sizes, int n_in,
                              void* d_out, int out_size, void* d_ws, size_t ws_size,
                              hipStream_t stream) {
    const int*   tokens = (const int*)  d_in[0];
    const float* emb    = (const float*)d_in[1];
    const float* W0     = (const float*)d_in[2];
    const float* U0     = (const float*)d_in[3];
    const float* b0     = (const float*)d_in[4];
    const float* W1     = (const float*)d_in[5];
    const float* U1     = (const float*)d_in[6];
    const float* b1     = (const float*)d_in[7];
    const float* Wd     = (const float*)d_in[8];
    const float* bd     = (const float*)d_in[9];
    float* out = (float*)d_out;

    // ws layout (bytes):
    // [Wt0 3MB][Wt1 4MB][h0 ring x4 1MB][h1 ring x2 0.5MB][bars 32KB][xbf 32MB]
    const size_t oWt0 = 0;
    const size_t oWt1 = (size_t)G4 * 768 * 2;                 // 3,145,728
    const size_t oH0  = oWt1 + (size_t)G4 * 1024 * 2;         // 7,340,032
    const size_t oH1  = oH0 + (size_t)4 * BB * UU * 2;        // +1,048,576
    const size_t oBar = oH1 + (size_t)2 * BB * UU * 2;        // +524,288
    const size_t oX   = oBar + 32768;
    const size_t needFull = oX + (size_t)TT * BB * EE * 2;    // ~42.5 MB
    int use_xbf = (ws_size >= needFull) ? 1 : 0;

    unsigned short* Wt0p = (unsigned short*)((char*)d_ws + oWt0);
    unsigned short* Wt1p = (unsigned short*)((char*)d_ws + oWt1);
    unsigned short* h0p  = (unsigned short*)((char*)d_ws + oH0);
    unsigned short* h1p  = (unsigned short*)((char*)d_ws + oH1);
    unsigned int*   barp = (unsigned int*)  ((char*)d_ws + oBar);
    unsigned short* xbfp = (unsigned short*)((char*)d_ws + oX);

    hipMemsetAsync((char*)d_ws + oH0, 0, oX - oH0, stream);

    wtrans<<<dim3(G4 / 32, EE / 32), dim3(32, 8), 0, stream>>>(W0, EE, Wt0p, 768, 0);
    wtrans<<<dim3(G4 / 32, UU / 32), dim3(32, 8), 0, stream>>>(U0, UU, Wt0p, 768, 256);
    wtrans<<<dim3(G4 / 32, UU / 32), dim3(32, 8), 0, stream>>>(W1, UU, Wt1p, 1024, 0);
    wtrans<<<dim3(G4 / 32, UU / 32), dim3(32, 8), 0, stream>>>(U1, UU, Wt1p, 1024, 512);

    if (use_xbf)
        xgather<<<dim3(BB * TT), dim3(64), 0, stream>>>(tokens, emb, xbfp);

    {
        const size_t shmem = 131072 + 3072 + 256;   // wl + hst + tokl
        hipFuncSetAttribute((const void*)rnn_persist,
                            hipFuncAttributeMaxDynamicSharedMemorySize, (int)shmem);
        void* args[] = {(void*)&Wt0p, (void*)&Wt1p, (void*)&xbfp,
                        (void*)&tokens, (void*)&emb, (void*)&b0, (void*)&b1,
                        (void*)&h0p, (void*)&h1p, (void*)&barp, (void*)&use_xbf};
        hipLaunchCooperativeKernel((const void*)rnn_persist, dim3(256), dim3(256),
                                   args, shmem, stream);
    }

    dense_out<<<dim3(BB), dim3(64), 0, stream>>>(h1p, Wd, bd, out);   // h1(256) = slot 0
}

// Round 5
// 3112.127 us; speedup vs baseline: 1.1417x; 1.0142x over previous
//
#include <hip/hip_runtime.h>
#include <hip/hip_bf16.h>
#include <math.h>

#define VB 50000
#define EE 256
#define UU 512
#define BB 256
#define TT 256
#define G4 2048

typedef __attribute__((ext_vector_type(8))) short short8;
typedef __attribute__((ext_vector_type(4))) float f32x4;

__device__ __forceinline__ float sigf(float x){ return 1.0f/(1.0f+expf(-x)); }
__device__ __forceinline__ unsigned short f2bf(float f){
    __hip_bfloat16 h = __float2bfloat16(f);   // RNE
    unsigned short s; __builtin_memcpy(&s,&h,2); return s;
}
__device__ __forceinline__ float bf2f(unsigned short u){
    unsigned int x = ((unsigned int)u)<<16; float f; __builtin_memcpy(&f,&x,4); return f;
}

// 16-byte device-coherent load as 2x8B agent-scope relaxed atomics (bypass
// stale per-CU L1 / per-XCD L2; served at the coherent point).
struct AF { unsigned long long a, b; };
__device__ __forceinline__ AF cload16(const unsigned short* p){
    const unsigned long long* q = (const unsigned long long*)p;
    AF r;
    r.a = __hip_atomic_load(q,   __ATOMIC_RELAXED, __HIP_MEMORY_SCOPE_AGENT);
    r.b = __hip_atomic_load(q+1, __ATOMIC_RELAXED, __HIP_MEMORY_SCOPE_AGENT);
    return r;
}
__device__ __forceinline__ short8 af2v(AF x){
    union { unsigned long long u[2]; short8 v; } c; c.u[0]=x.a; c.u[1]=x.b; return c.v;
}
__device__ __forceinline__ unsigned int cldu(const unsigned int* p){
    return __hip_atomic_load(p, __ATOMIC_RELAXED, __HIP_MEMORY_SCOPE_AGENT);
}
__device__ __forceinline__ void cstu(unsigned int* p, unsigned int v){
    __hip_atomic_store(p, v, __ATOMIC_RELAXED, __HIP_MEMORY_SCOPE_AGENT);
}

// ---------- pre-pass: transpose+convert W [rows][2048] fp32 -> out[c][koff+k] bf16 ----------
__global__ __launch_bounds__(256) void wtrans(const float* __restrict__ in, int rows,
                                              unsigned short* __restrict__ out,
                                              int Kout, int koff) {
    __shared__ float tl[32][33];
    int tx = threadIdx.x, ty = threadIdx.y;
    int c0 = blockIdx.x * 32, k0 = blockIdx.y * 32;
    #pragma unroll
    for (int i = 0; i < 4; i++)
        tl[ty + i * 8][tx] = in[(size_t)(k0 + ty + i * 8) * G4 + c0 + tx];
    __syncthreads();
    #pragma unroll
    for (int i = 0; i < 4; i++)
        out[(size_t)(c0 + ty + i * 8) * Kout + koff + k0 + tx] = f2bf(tl[tx][ty + i * 8]);
}

// ---------- pre-pass: gather embeddings -> xbf[t][b][k] bf16 ----------
__global__ __launch_bounds__(64) void xgather(const int* __restrict__ tokens,
                                              const float* __restrict__ emb,
                                              unsigned short* __restrict__ xbf) {
    int flat = blockIdx.x;
    int b = flat & 255, t = flat >> 8;
    int tok = tokens[b * TT + t];
    float4 v = ((const float4*)(emb + (size_t)tok * EE))[threadIdx.x];
    ushort4 o;
    o.x = f2bf(v.x); o.y = f2bf(v.y); o.z = f2bf(v.z); o.w = f2bf(v.w);
    ((ushort4*)(xbf + ((size_t)t * BB + b) * EE))[threadIdx.x] = o;
}

// ---------- persistent 2-layer LSTM ----------
// STRUCTURE = round-4 verbatim (verified: 3117us, absmax 0.0).
// ONE change this round: ANTI-CLOCK-DROOP busy-work in the poll spin loop.
// Rationale: critical-path arithmetic at 2.4GHz gives ~1.05us/step; observed
// 12.2us/step (11.6x). No counter explains it (conflicts fixed->no change,
// poll coalescing->no change, FETCH modest). 2500cy at ~210MHz = 12us exactly:
// suspected DPM clock-park on a ~9%-active kernel. Fix: while waiting in the
// poll loop, issue full-rate INDEPENDENT v_fma chains (4 parallel chains,
// 64 instrs/iter) so every CU presents continuous VALU activity. Arithmetic
// path untouched -> absmax must remain 0.0.
__global__ __launch_bounds__(256, 1) void rnn_persist(
    const unsigned short* __restrict__ Wt0,   // [2048][768]  bf16 [col][k]
    const unsigned short* __restrict__ Wt1,   // [2048][1024]
    const unsigned short* __restrict__ xbf,   // [256][256][256] bf16 (or unused)
    const int* __restrict__ tokens, const float* __restrict__ emb,
    const float* __restrict__ b0v, const float* __restrict__ b1v,
    unsigned short* __restrict__ h0buf,       // [4][256][512] bf16 ring
    unsigned short* __restrict__ h1buf,       // [2][256][512] bf16 ring
    unsigned int* __restrict__ bars,          // per group 1024 uints (4KB)
    int use_xbf)
{
    extern __shared__ char smem[];
    unsigned short* wl  = (unsigned short*)smem;               // lane-ordered weights (<=128KB)
    unsigned short* hst = (unsigned short*)(smem + 131072);    // 64x16 h staging, stride 24 (3KB)
    int*            tokl = (int*)(smem + 131072 + 3072);       // 64 ints

    const int tid   = threadIdx.x;
    const int bid   = blockIdx.x;
    const int g     = bid >> 6;
    const int local = bid & 63;
    const int layer = local >> 5;
    const int u0    = (local & 31) * 16;
    const int row0  = g * 64;
    const int K     = layer ? 1024 : 768;
    const int KT    = K / 32;                  // 24 or 32 k-tiles
    const unsigned short* Wt = layer ? Wt1 : Wt0;
    const float* bR = layer ? b1v : b0v;

    // ---- fill LDS weights, LANE-ordered chunks: i = ((gate*KT+kt)*64 + (q*16+n)) ----
    const int nch = 4 * KT * 64;
    for (int i = tid; i < nch; i += 256) {
        int n  = i & 15;
        int q2 = (i >> 4) & 3;
        int t2 = i >> 6;
        int kt = t2 % KT, gate = t2 / KT;
        const unsigned short* src = Wt + (size_t)(gate * UU + u0 + n) * K + kt * 32 + q2 * 8;
        *(short8*)(wl + (size_t)i * 8) = *(const short8*)src;
    }

    float gb[4];
    #pragma unroll
    for (int gate = 0; gate < 4; gate++) gb[gate] = bR[gate * UU + u0 + (tid & 15)];
    float cst[4] = {0.f, 0.f, 0.f, 0.f};

    const int lane = tid & 63;
    const int w    = tid >> 6;
    const int n16  = lane & 15;
    const int q    = lane >> 4;
    const int q8   = q * 8;
    const int myrow = row0 + w * 16 + n16;
    const unsigned short* wlane = wl + lane * 8;   // + (gate*KT+kt)*512 shorts

    // flag region for this group: flag(local) at 4B stride (coalesced polls)
    unsigned int* flg = bars + (size_t)g * 1024;
    unsigned int* myFlag = flg + local;
    // per-lane poll target: lane L polls flag of block L
    const unsigned int* pollp = flg + lane;
    const int pollSlack = (layer == 0 && lane >= 32) ? 2 : 0;  // L0 waits L1>=p-2

    const size_t HS = (size_t)BB * UU;

    // anti-droop dummy state (kept live via asm at loop exit)
    float z0 = 1.0f + lane, z1 = 2.0f + lane, z2 = 3.0f + lane, z3 = 4.0f + lane;

    __syncthreads();   // wl ready

    for (int p = 0; p <= TT; p++) {
        const bool active = layer ? (p >= 1) : (p < TT);
        const bool wait_needed = layer ? (p >= 1) : (p < TT);

        f32x4 acc[4];
        #pragma unroll
        for (int gate = 0; gate < 4; gate++)
            acc[gate] = (f32x4){gb[gate], gb[gate], gb[gate], gb[gate]};

        // ---- L0 x-part precompute (static inputs only) BEFORE the wait ----
        if (layer == 0 && p < TT) {
            if (!use_xbf) {
                if (tid < 64) tokl[tid] = tokens[(size_t)(row0 + tid) * TT + p];
                __syncthreads();
                const float* ep = emb + (size_t)tokl[w * 16 + n16] * EE + q8;
                #pragma unroll
                for (int kt = 0; kt < 8; kt++) {
                    float4 f0 = *(const float4*)(ep + kt * 32);
                    float4 f1 = *(const float4*)(ep + kt * 32 + 4);
                    union { unsigned short s[8]; short8 v; } u;
                    u.s[0]=f2bf(f0.x); u.s[1]=f2bf(f0.y); u.s[2]=f2bf(f0.z); u.s[3]=f2bf(f0.w);
                    u.s[4]=f2bf(f1.x); u.s[5]=f2bf(f1.y); u.s[6]=f2bf(f1.z); u.s[7]=f2bf(f1.w);
                    #pragma unroll
                    for (int gate = 0; gate < 4; gate++) {
                        short8 bv = *(const short8*)(wlane + (size_t)(gate * KT + kt) * 512);
                        acc[gate] = __builtin_amdgcn_mfma_f32_16x16x32_bf16(u.v, bv, acc[gate], 0, 0, 0);
                    }
                }
            } else {
                const unsigned short* xp = xbf + ((size_t)p * BB + myrow) * EE + q8;
                #pragma unroll
                for (int kt = 0; kt < 8; kt++) {
                    short8 av = *(const short8*)(xp + kt * 32);
                    #pragma unroll
                    for (int gate = 0; gate < 4; gate++) {
                        short8 bv = *(const short8*)(wlane + (size_t)(gate * KT + kt) * 512);
                        acc[gate] = __builtin_amdgcn_mfma_f32_16x16x32_bf16(av, bv, acc[gate], 0, 0, 0);
                    }
                }
            }
        }

        // ---- per-wave direct poll with full-rate VALU busy-work (anti-droop) ----
        if (wait_needed) {
            const int thr = p - pollSlack;
            for (;;) {
                bool bad = ((int)cldu(pollp) < thr);
                if (__ballot(bad) == 0ULL) break;
                // 4 independent FMA chains, 64 instrs/iter: keeps the SIMD
                // issue port saturated while we wait so the clock governor
                // never sees an idle CU. No effect on kernel results.
                #pragma unroll
                for (int it = 0; it < 16; it++) {
                    z0 = __builtin_fmaf(z0, 1.0000001f, 1e-7f);
                    z1 = __builtin_fmaf(z1, 1.0000001f, 1e-7f);
                    z2 = __builtin_fmaf(z2, 1.0000001f, 1e-7f);
                    z3 = __builtin_fmaf(z3, 1.0000001f, 1e-7f);
                }
            }
        }

        // ---- dynamic (h-dependent) part: register-bounded A pipeline ----
        if (active) {
            const unsigned short* h0r = h0buf + (size_t)(p & 3) * HS;
            unsigned short* hw;

            if (layer) {
                const unsigned short* h1r = h1buf + (size_t)((p + 1) & 1) * HS;  // h1(p-1)
                hw = h1buf + (size_t)(p & 1) * HS;
                const unsigned short* a0 = h0r + (size_t)myrow * UU + q8;
                const unsigned short* a1 = h1r + (size_t)myrow * UU + q8;
                AF ab[2][8];
                #pragma unroll
                for (int i = 0; i < 8; i++) ab[0][i] = cload16(a0 + i * 32);  // stage 0
                #pragma unroll
                for (int s = 0; s < 4; s++) {
                    const int cur = s & 1, nxt = cur ^ 1;
                    if (s < 3) {
                        #pragma unroll
                        for (int i = 0; i < 8; i++) {
                            int kt = (s + 1) * 8 + i;
                            const unsigned short* ap = (kt < 16) ? (a0 + kt * 32)
                                                                 : (a1 + (kt - 16) * 32);
                            ab[nxt][i] = cload16(ap);
                        }
                    }
                    #pragma unroll
                    for (int i = 0; i < 8; i++) {
                        int kt = s * 8 + i;
                        short8 av = af2v(ab[cur][i]);
                        #pragma unroll
                        for (int gate = 0; gate < 4; gate++) {
                            short8 bv = *(const short8*)(wlane + (size_t)(gate * KT + kt) * 512);
                            acc[gate] = __builtin_amdgcn_mfma_f32_16x16x32_bf16(av, bv, acc[gate], 0, 0, 0);
                        }
                    }
                }
            } else {
                hw = h0buf + (size_t)((p + 1) & 3) * HS;
                const unsigned short* ah = h0r + (size_t)myrow * UU + q8;
                AF ab[2][8];
                #pragma unroll
                for (int i = 0; i < 8; i++) ab[0][i] = cload16(ah + i * 32);  // kt 8..15
                #pragma unroll
                for (int s = 0; s < 2; s++) {
                    const int cur = s & 1, nxt = cur ^ 1;
                    if (s < 1) {
                        #pragma unroll
                        for (int i = 0; i < 8; i++)
                            ab[nxt][i] = cload16(ah + (8 + i) * 32);          // kt 16..23
                    }
                    #pragma unroll
                    for (int i = 0; i < 8; i++) {
                        int kt = 8 + s * 8 + i;
                        short8 av = af2v(ab[cur][i]);
                        #pragma unroll
                        for (int gate = 0; gate < 4; gate++) {
                            short8 bv = *(const short8*)(wlane + (size_t)(gate * KT + kt) * 512);
                            acc[gate] = __builtin_amdgcn_mfma_f32_16x16x32_bf16(av, bv, acc[gate], 0, 0, 0);
                        }
                    }
                }
            }

            // gating (D layout: col=n16 -> u, row=q*4+r); stage h to LDS (stride 24)
            #pragma unroll
            for (int r = 0; r < 4; r++) {
                float zi = acc[0][r];
                float zf = acc[1][r];
                float zg = acc[2][r];
                float zo = acc[3][r];
                float cn = sigf(zf) * cst[r] + sigf(zi) * tanhf(zg);
                cst[r] = cn;
                hst[(w * 16 + q * 4 + r) * 24 + n16] = f2bf(sigf(zo) * tanhf(cn));
            }
            __syncthreads();   // hst complete (block-uniform path)
            if (tid < 128) {   // coalesced coherent store: 128 threads x 16B
                int row = tid >> 1, half = tid & 1;
                const unsigned long long* s = (const unsigned long long*)(hst + row * 24 + half * 8);
                unsigned long long* dp = (unsigned long long*)(hw + (size_t)(row0 + row) * UU + u0 + half * 8);
                __hip_atomic_store(dp,     s[0], __ATOMIC_RELAXED, __HIP_MEMORY_SCOPE_AGENT);
                __hip_atomic_store(dp + 1, s[1], __ATOMIC_RELAXED, __HIP_MEMORY_SCOPE_AGENT);
            }
        }

        // ---- arrive(p): every wave drains its own vmem, then tid0 flags ----
        if (p < TT) {
            asm volatile("s_waitcnt vmcnt(0)" ::: "memory");
            __syncthreads();
            if (tid == 0) cstu(myFlag, (unsigned int)(p + 1));
        }
    }

    // keep the dummy chains live (never taken branch writes them out)
    if (tid == 100000) {
        volatile float sink = z0 + z1 + z2 + z3;
        (void)sink;
    }
}

// ---------- final dense: out[b] = sigmoid(h1 . Wd + bd) ----------
__global__ __launch_bounds__(64) void dense_out(
    const unsigned short* __restrict__ h, const float* __restrict__ Wd,
    const float* __restrict__ bd, float* __restrict__ out)
{
    int b = blockIdx.x;
    int lane = threadIdx.x;
    float s = 0.f;
    #pragma unroll
    for (int k = lane; k < UU; k += 64) s += bf2f(h[(size_t)b * UU + k]) * Wd[k];
    #pragma unroll
    for (int off = 32; off > 0; off >>= 1) s += __shfl_down(s, off);
    if (lane == 0) out[b] = sigf(s + bd[0]);
}

extern "C" void kernel_launch(void* const* d_in, const int* in_sizes, int n_in,
                              void* d_out, int out_size, void* d_ws, size_t ws_size,
                              hipStream_t stream) {
    const int*   tokens = (const int*)  d_in[0];
    const float* emb    = (const float*)d_in[1];
    const float* W0     = (const float*)d_in[2];
    const float* U0     = (const float*)d_in[3];
    const float* b0     = (const float*)d_in[4];
    const float* W1     = (const float*)d_in[5];
    const float* U1     = (const float*)d_in[6];
    const float* b1     = (const float*)d_in[7];
    const float* Wd     = (const float*)d_in[8];
    const float* bd     = (const float*)d_in[9];
    float* out = (float*)d_out;

    // ws layout (bytes):
    // [Wt0 3MB][Wt1 4MB][h0 ring x4 1MB][h1 ring x2 0.5MB][bars 32KB][xbf 32MB]
    const size_t oWt0 = 0;
    const size_t oWt1 = (size_t)G4 * 768 * 2;                 // 3,145,728
    const size_t oH0  = oWt1 + (size_t)G4 * 1024 * 2;         // 7,340,032
    const size_t oH1  = oH0 + (size_t)4 * BB * UU * 2;        // +1,048,576
    const size_t oBar = oH1 + (size_t)2 * BB * UU * 2;        // +524,288
    const size_t oX   = oBar + 32768;
    const size_t needFull = oX + (size_t)TT * BB * EE * 2;    // ~42.5 MB
    int use_xbf = (ws_size >= needFull) ? 1 : 0;

    unsigned short* Wt0p = (unsigned short*)((char*)d_ws + oWt0);
    unsigned short* Wt1p = (unsigned short*)((char*)d_ws + oWt1);
    unsigned short* h0p  = (unsigned short*)((char*)d_ws + oH0);
    unsigned short* h1p  = (unsigned short*)((char*)d_ws + oH1);
    unsigned int*   barp = (unsigned int*)  ((char*)d_ws + oBar);
    unsigned short* xbfp = (unsigned short*)((char*)d_ws + oX);

    hipMemsetAsync((char*)d_ws + oH0, 0, oX - oH0, stream);

    wtrans<<<dim3(G4 / 32, EE / 32), dim3(32, 8), 0, stream>>>(W0, EE, Wt0p, 768, 0);
    wtrans<<<dim3(G4 / 32, UU / 32), dim3(32, 8), 0, stream>>>(U0, UU, Wt0p, 768, 256);
    wtrans<<<dim3(G4 / 32, UU / 32), dim3(32, 8), 0, stream>>>(W1, UU, Wt1p, 1024, 0);
    wtrans<<<dim3(G4 / 32, UU / 32), dim3(32, 8), 0, stream>>>(U1, UU, Wt1p, 1024, 512);

    if (use_xbf)
        xgather<<<dim3(BB * TT), dim3(64), 0, stream>>>(tokens, emb, xbfp);

    {
        const size_t shmem = 131072 + 3072 + 256;   // wl + hst + tokl
        hipFuncSetAttribute((const void*)rnn_persist,
                            hipFuncAttributeMaxDynamicSharedMemorySize, (int)shmem);
        void* args[] = {(void*)&Wt0p, (void*)&Wt1p, (void*)&xbfp,
                        (void*)&tokens, (void*)&emb, (void*)&b0, (void*)&b1,
                        (void*)&h0p, (void*)&h1p, (void*)&barp, (void*)&use_xbf};
        hipLaunchCooperativeKernel((const void*)rnn_persist, dim3(256), dim3(256),
                                   args, shmem, stream);
    }

    dense_out<<<dim3(BB), dim3(64), 0, stream>>>(h1p, Wd, bd, out);   // h1(256) = slot 0
}